// Round 14
// baseline (816.422 us; speedup 1.0000x reference)
//
#include <hip/hip_runtime.h>

typedef _Float16 f16x8 __attribute__((ext_vector_type(8)));
typedef _Float16 f16x4 __attribute__((ext_vector_type(4)));
typedef float    f32x4 __attribute__((ext_vector_type(4)));

// ---------------------------------------------------------------- helpers

__device__ __forceinline__ void async16(void* lds, const void* g) {
    __builtin_amdgcn_global_load_lds(
        (const __attribute__((address_space(1))) unsigned int*)g,
        (__attribute__((address_space(3))) unsigned int*)lds, 16, 0, 0);
}

#define MEMF() asm volatile("" ::: "memory")
#define VMWAIT(N) asm volatile("s_waitcnt vmcnt(" #N ")" ::: "memory")
#define LGKM0()   asm volatile("s_waitcnt lgkmcnt(0)" ::: "memory")
#define SBAR0()   __builtin_amdgcn_sched_barrier(0)

// swizzled LDS fragment read within a private 128x32 fp16 panel (64B rows);
// byte col XORed by ((row>>1)&3)<<4 -> conflict-free for the 16x16 pattern
// (measured 0 SQ_LDS_BANK_CONFLICT across r4-r13)
__device__ __forceinline__ f16x8 frag_ld(const _Float16* buf, int row, int kq) {
    const char* p = (const char*)buf + row * 64 + ((kq << 4) ^ (((row >> 1) & 3) << 4));
    return *(const f16x8*)p;
}

// ---------------------------------------- barrier-free private-staging GEMM
// A [M][K] fp16, BT [N][K] fp16, z = (A*BT^T)*alpha+beta -> fp16 Z or fp32 C
// 256x256 block tile, 4 fat waves (2Mx2N, each owns 128x128 output).
// EACH WAVE stages its own A(128xBK) + B(128xBK) panels into a PRIVATE 32KB
// LDS region (ring-2) with its own global_load_lds; consumption gated only by
// per-wave vmcnt/lgkmcnt. ZERO barriers in the K-loop: waves free-run and
// phase-drift (seeded by s_sleep stagger), so one wave's MFMA covers another
// wave's LDS/VMEM bursts -- removes the lockstep that pinned r4-r13 at ~40%.
//
// Per-wave ledger (no cross-wave hazards; regions private):
//   loop i: READ frags(slot i&1) ; LGKM0 (frags in regs)
//           STG(slot i&1 <- tile i+2)   [WAR ok: reads completed]
//           64x MFMA ; VMWAIT(16)       [FIFO => tile i+1 resident]
// Prologue: STG(0,t0) STG(1,t1) VMWAIT(16). Tail: peel 2 (VMWAIT(0), none).

__global__ __launch_bounds__(256, 1) void gemm_f16_bn_nb(
        const _Float16* __restrict__ A, const _Float16* __restrict__ BT,
        float* __restrict__ C, _Float16* __restrict__ Z,
        const float* __restrict__ bias, const float* __restrict__ mean,
        const float* __restrict__ var,  const float* __restrict__ bnw,
        const float* __restrict__ bnb,  const float* __restrict__ scalep,
        int M, int N, int K) {
    __shared__ __align__(16) char lds[4 * 32768];   // 4 waves x (2 ring x (A8K+B8K))

    // bijective XCD swizzle (grid = 1024, divisible by 8)
    const int nwg = gridDim.x;
    const int cpx = nwg >> 3;
    int bid = blockIdx.x;
    int swz = ((nwg & 7) == 0) ? (bid & 7) * cpx + (bid >> 3) : bid;
    const int ntn = N >> 8;
    const int m0 = (swz / ntn) << 8, n0 = (swz % ntn) << 8;

    const int t = threadIdx.x;                      // 0..255
    const int lane = t & 63, wid = t >> 6;          // 4 waves
    const int wr = wid >> 1, wc = wid & 1;          // 2M x 2N
    const int rr = lane & 15, kq = lane >> 4;

    char* const myLds = lds + wid * 32768;          // private region
    char* const dA = myLds + (size_t)lane * 16;     // + slot*16384 + j*1024
    char* const dB = myLds + 8192 + (size_t)lane * 16;

    // per-lane global source pointers for the 8 A / 8 B staging instrs.
    // chunk c = j*64+lane: local row = j*16+(lane>>2), 16B slot = lane&3,
    // source col pre-XORed by the read swizzle (both-sides involution).
    const _Float16* pA[8];
    const _Float16* pB[8];
#pragma unroll
    for (int j = 0; j < 8; j++) {
        const int row = j * 16 + (lane >> 2);
        const int xc = (((lane & 3) ^ ((row >> 1) & 3)) << 3);
        pA[j] = A  + (size_t)(m0 + wr * 128 + row) * K + xc;
        pB[j] = BT + (size_t)(n0 + wc * 128 + row) * K + xc;
    }

#define STG(S, T_) do {                                                   \
    const size_t co_ = (size_t)(T_) * 32;                                 \
    _Pragma("unroll")                                                     \
    for (int j = 0; j < 8; j++)                                           \
        async16(dA + (S) * 16384 + j * 1024, pA[j] + co_);                \
    _Pragma("unroll")                                                     \
    for (int j = 0; j < 8; j++)                                           \
        async16(dB + (S) * 16384 + j * 1024, pB[j] + co_);                \
  } while (0)

    f32x4 acc[8][8] = {};                           // 256 VGPR accumulator

    const int NT = K >> 5;   // host gate: >= 4

    // prologue: stage tiles 0,1 into private ring
    STG(0, 0);
    STG(1, 1);
    VMWAIT(16);       // own tile-0 loads done (tile-1's 16 in flight)

    // seed phase-drift: waves on different SIMDs start offset ~256*wid cyc
    for (int j = 0; j < wid; j++) __builtin_amdgcn_s_sleep(4);

#define TILE_BODY(S, STAGE, KSRC, WAITSTMT)                                      \
  do {                                                                           \
    const _Float16* Ab = (const _Float16*)(myLds + (S) * 16384);                 \
    const _Float16* Bb = (const _Float16*)(myLds + (S) * 16384 + 8192);          \
    f16x8 af[8], bf[8];                                                          \
    _Pragma("unroll")                                                            \
    for (int mi = 0; mi < 8; mi++) af[mi] = frag_ld(Ab, mi * 16 + rr, kq);       \
    _Pragma("unroll")                                                            \
    for (int ni = 0; ni < 8; ni++) bf[ni] = frag_ld(Bb, ni * 16 + rr, kq);       \
    LGKM0();                        /* frags in regs: slot reusable (WAR) */     \
    if (STAGE) STG(S, KSRC);                                                     \
    SBAR0();                        /* pin stage issue before MFMA cluster */    \
    __builtin_amdgcn_s_setprio(1);                                               \
    _Pragma("unroll")                                                            \
    for (int ni = 0; ni < 8; ni++) {                                             \
      _Pragma("unroll")                                                          \
      for (int mi = 0; mi < 8; mi++)                                             \
        acc[mi][ni] = __builtin_amdgcn_mfma_f32_16x16x32_f16(                    \
            af[mi], bf[ni], acc[mi][ni], 0, 0, 0);                               \
    }                                                                            \
    __builtin_amdgcn_s_setprio(0);                                               \
    WAITSTMT;                       /* FIFO: next tile resident */               \
  } while (0)

    int ti = 0;
    for (; ti < NT - 2; ++ti)
        TILE_BODY(ti & 1, 1, ti + 2, VMWAIT(16));
    TILE_BODY(ti & 1, 0, 0, VMWAIT(0)); ++ti;
    TILE_BODY(ti & 1, 0, 0, (void)0);
#undef TILE_BODY
#undef STG

    // fused BN-affine epilogue (r10-verified fat-wave layout): fp16 Z or fp32 C
    const float s = scalep[0];
    const int colb = n0 + wc * 128 + rr;
    const int rowb = m0 + wr * 128 + (kq << 2);
#pragma unroll
    for (int ni = 0; ni < 8; ni++) {
        const int col = colb + ni * 16;
        const float rv    = rsqrtf(var[col] + 1e-5f);
        const float alpha = rv * bnw[col] * s;
        const float beta  = (bias[col] - mean[col]) * alpha + bnb[col] * s;
#pragma unroll
        for (int mi = 0; mi < 8; mi++)
#pragma unroll
            for (int i = 0; i < 4; i++) {
                const float v = acc[mi][ni][i] * alpha + beta;
                const size_t off = (size_t)(rowb + mi * 16 + i) * N + col;
                if (Z) Z[off] = (_Float16)v;
                else   __builtin_nontemporal_store(v, &C[off]);
            }
    }
}

// ---------------------------------------------------------------- converts

__global__ __launch_bounds__(256) void cvt_x_kernel(const float4* __restrict__ in,
                                                    f16x4* __restrict__ outp, long n4) {
    long i = (long)blockIdx.x * blockDim.x + threadIdx.x;
    const long stride = (long)gridDim.x * blockDim.x;
    for (; i < n4; i += stride) {
        float4 v = in[i];
        f16x4 h = { (_Float16)v.x, (_Float16)v.y, (_Float16)v.z, (_Float16)v.w };
        outp[i] = h;
    }
}

// w [K][N] fp32 -> wt [N][K] fp16
__global__ __launch_bounds__(256) void transpose_w_kernel(const float* __restrict__ w,
                                                          _Float16* __restrict__ wt,
                                                          int K, int N) {
    __shared__ _Float16 tile[32][33];
    const int n0 = blockIdx.x * 32;
    const int k0 = blockIdx.y * 32;
    for (int i = threadIdx.y; i < 32; i += 8)
        tile[i][threadIdx.x] = (_Float16)w[(size_t)(k0 + i) * N + n0 + threadIdx.x];
    __syncthreads();
    for (int i = threadIdx.y; i < 32; i += 8)
        wt[(size_t)(n0 + i) * K + k0 + threadIdx.x] = tile[threadIdx.x][i];
}

// ------------------------------------------------- fallback GEMM (no ws)

__device__ __forceinline__ void mfma_step_128(const _Float16* As, const _Float16* Bs,
                                              f32x4 (&acc)[4][4], int lane, int wr, int wc) {
    const int kk = (lane >> 4) * 8;
    const int rr = lane & 15;
    f16x8 af[4], bf[4];
#pragma unroll
    for (int mi = 0; mi < 4; mi++)
        af[mi] = *(const f16x8*)(As + (size_t)(wr * 64 + mi * 16 + rr) * 32 + kk);
#pragma unroll
    for (int ni = 0; ni < 4; ni++)
        bf[ni] = *(const f16x8*)(Bs + (size_t)(wc * 64 + ni * 16 + rr) * 32 + kk);
#pragma unroll
    for (int mi = 0; mi < 4; mi++)
#pragma unroll
        for (int ni = 0; ni < 4; ni++)
            acc[mi][ni] = __builtin_amdgcn_mfma_f32_16x16x32_f16(af[mi], bf[ni], acc[mi][ni], 0, 0, 0);
}

__global__ __launch_bounds__(256) void gemm_f32src_bn(const float* __restrict__ X,
                                                      const float* __restrict__ W,
                                                      float* __restrict__ C,
                                                      const float* __restrict__ bias,
                                                      const float* __restrict__ mean,
                                                      const float* __restrict__ var,
                                                      const float* __restrict__ bnw,
                                                      const float* __restrict__ bnb,
                                                      const float* __restrict__ scalep,
                                                      int M, int N, int K) {
    __shared__ _Float16 As[128 * 32];
    __shared__ _Float16 Bs[128 * 32];

    const int nwg = gridDim.x;
    const int cpx = nwg >> 3;
    int bid = blockIdx.x;
    int swz = ((nwg & 7) == 0) ? (bid & 7) * cpx + (bid >> 3) : bid;
    const int ntn = N / 128;
    const int m0 = (swz / ntn) * 128, n0 = (swz % ntn) * 128;

    const int t = threadIdx.x;
    const int lane = t & 63, w = t >> 6;
    const int wr = w >> 1, wc = w & 1;

    f32x4 acc[4][4] = {};

    for (int k0 = 0; k0 < K; k0 += 32) {
        __syncthreads();
#pragma unroll
        for (int p = 0; p < 4; p++) {
            const int r = p * 32 + (t >> 3);
            const int c = (t & 7) * 4;
            float4 v = *(const float4*)&X[(size_t)(m0 + r) * K + k0 + c];
            f16x4 h = { (_Float16)v.x, (_Float16)v.y, (_Float16)v.z, (_Float16)v.w };
            *(f16x4*)&As[(size_t)r * 32 + c] = h;
        }
#pragma unroll
        for (int p = 0; p < 4; p++) {
            const int kk = p * 8 + (t >> 5);
            const int nn = (t & 31) * 4;
            float4 v = *(const float4*)&W[(size_t)(k0 + kk) * N + n0 + nn];
            Bs[(size_t)(nn + 0) * 32 + kk] = (_Float16)v.x;
            Bs[(size_t)(nn + 1) * 32 + kk] = (_Float16)v.y;
            Bs[(size_t)(nn + 2) * 32 + kk] = (_Float16)v.z;
            Bs[(size_t)(nn + 3) * 32 + kk] = (_Float16)v.w;
        }
        __syncthreads();
        mfma_step_128(As, Bs, acc, lane, wr, wc);
    }

    const float s = scalep[0];
    const int colbase = n0 + wc * 64 + (lane & 15);
    const int rowbase = m0 + wr * 64 + ((lane >> 4) << 2);
#pragma unroll
    for (int ni = 0; ni < 4; ni++) {
        const int col = colbase + ni * 16;
        const float r     = rsqrtf(var[col] + 1e-5f);
        const float alpha = r * bnw[col] * s;
        const float beta  = (bias[col] - mean[col]) * alpha + bnb[col] * s;
#pragma unroll
        for (int mi = 0; mi < 4; mi++)
#pragma unroll
            for (int i = 0; i < 4; i++)
                C[(size_t)(rowbase + mi * 16 + i) * N + col] = acc[mi][ni][i] * alpha + beta;
    }
}

// ---------------------------------------------------------------- softmax

__global__ __launch_bounds__(256) void softmax_rows(float* __restrict__ out, int N) {
    __shared__ float red[8];
    float4* p = (float4*)(out + (size_t)blockIdx.x * N);
    const int t = threadIdx.x;
    const int lane = t & 63, wid = t >> 6;

    float4 v[4];
    float mx = -3.4e38f;
#pragma unroll
    for (int i = 0; i < 4; i++) {
        v[i] = p[t + 256 * i];
        mx = fmaxf(mx, fmaxf(fmaxf(v[i].x, v[i].y), fmaxf(v[i].z, v[i].w)));
    }
#pragma unroll
    for (int off = 32; off >= 1; off >>= 1) mx = fmaxf(mx, __shfl_xor(mx, off));
    if (lane == 0) red[wid] = mx;
    __syncthreads();
    mx = fmaxf(fmaxf(red[0], red[1]), fmaxf(red[2], red[3]));

    float sum = 0.f;
#pragma unroll
    for (int i = 0; i < 4; i++) {
        v[i].x = __expf(v[i].x - mx); v[i].y = __expf(v[i].y - mx);
        v[i].z = __expf(v[i].z - mx); v[i].w = __expf(v[i].w - mx);
        sum += v[i].x + v[i].y + v[i].z + v[i].w;
    }
#pragma unroll
    for (int off = 32; off >= 1; off >>= 1) sum += __shfl_xor(sum, off);
    if (lane == 0) red[4 + wid] = sum;
    __syncthreads();
    sum = red[4] + red[5] + red[6] + red[7];

    const float inv = 1.0f / sum;
#pragma unroll
    for (int i = 0; i < 4; i++) {
        v[i].x *= inv; v[i].y *= inv; v[i].z *= inv; v[i].w *= inv;
        p[t + 256 * i] = v[i];
    }
}

// fp16-z variant: reads z fp16 (half the read bytes), writes fp32 probs
__global__ __launch_bounds__(256) void softmax_rows_h(const _Float16* __restrict__ z,
                                                      float* __restrict__ out, int N) {
    __shared__ float red[8];
    const _Float16* zr = z + (size_t)blockIdx.x * N;
    float4* o4 = (float4*)(out + (size_t)blockIdx.x * N);
    const int t = threadIdx.x;
    const int lane = t & 63, wid = t >> 6;

    f16x8 h0 = *(const f16x8*)(zr + t * 8);
    f16x8 h1 = *(const f16x8*)(zr + 2048 + t * 8);
    float v[16];
#pragma unroll
    for (int i = 0; i < 8; i++) { v[i] = (float)h0[i]; v[8 + i] = (float)h1[i]; }

    float mx = -3.4e38f;
#pragma unroll
    for (int i = 0; i < 16; i++) mx = fmaxf(mx, v[i]);
#pragma unroll
    for (int off = 32; off >= 1; off >>= 1) mx = fmaxf(mx, __shfl_xor(mx, off));
    if (lane == 0) red[wid] = mx;
    __syncthreads();
    mx = fmaxf(fmaxf(red[0], red[1]), fmaxf(red[2], red[3]));

    float sum = 0.f;
#pragma unroll
    for (int i = 0; i < 16; i++) { v[i] = __expf(v[i] - mx); sum += v[i]; }
#pragma unroll
    for (int off = 32; off >= 1; off >>= 1) sum += __shfl_xor(sum, off);
    if (lane == 0) red[4 + wid] = sum;
    __syncthreads();
    sum = red[4] + red[5] + red[6] + red[7];

    const float inv = 1.0f / sum;
    float4 o;
#pragma unroll
    for (int c = 0; c < 4; c++) {
        o.x = v[c * 4 + 0] * inv; o.y = v[c * 4 + 1] * inv;
        o.z = v[c * 4 + 2] * inv; o.w = v[c * 4 + 3] * inv;
        o4[(c >> 1) * 512 + t * 2 + (c & 1)] = o;
    }
}

// ---------------------------------------------------------------- launch

extern "C" void kernel_launch(void* const* d_in, const int* in_sizes, int n_in,
                              void* d_out, int out_size, void* d_ws, size_t ws_size,
                              hipStream_t stream) {
    const float* x     = (const float*)d_in[0];
    const float* w     = (const float*)d_in[1];
    const float* bias  = (const float*)d_in[2];
    const float* mean  = (const float*)d_in[3];
    const float* var   = (const float*)d_in[4];
    const float* bnw   = (const float*)d_in[5];
    const float* bnb   = (const float*)d_in[6];
    const float* scale = (const float*)d_in[7];
    float* out = (float*)d_out;

    const int N = in_sizes[2];
    const int K = in_sizes[1] / N;
    const int M = in_sizes[0] / K;

    const size_t xh_bytes = (size_t)M * K * sizeof(_Float16);
    const size_t wh_bytes = (size_t)N * K * sizeof(_Float16);
    const size_t zh_bytes = (size_t)M * N * sizeof(_Float16);
    const int NT = K >> 5;

    if (ws_size >= xh_bytes + wh_bytes && (M & 255) == 0 && (N & 255) == 0 &&
        NT >= 4 && (K & 31) == 0) {
        _Float16* x16 = (_Float16*)d_ws;
        _Float16* wt16 = (_Float16*)((char*)d_ws + xh_bytes);
        const bool zf16 = (ws_size >= xh_bytes + wh_bytes + zh_bytes) && (N & 4095) == 0;
        _Float16* z16 = zf16 ? (_Float16*)((char*)d_ws + xh_bytes + wh_bytes) : nullptr;

        cvt_x_kernel<<<2048, 256, 0, stream>>>((const float4*)x, (f16x4*)x16,
                                               (long)M * K / 4);
        transpose_w_kernel<<<dim3(N / 32, K / 32), dim3(32, 8), 0, stream>>>(w, wt16, K, N);
        const int nblocks = (M >> 8) * (N >> 8);
        gemm_f16_bn_nb<<<nblocks, 256, 0, stream>>>(x16, wt16, out, z16, bias, mean,
                                                    var, bnw, bnb, scale, M, N, K);
        if (zf16) softmax_rows_h<<<M, 256, 0, stream>>>(z16, out, N);
        else      softmax_rows<<<M, 256, 0, stream>>>(out, N);
    } else {
        const int nblocks = (M / 128) * (N / 128);
        gemm_f32src_bn<<<nblocks, 256, 0, stream>>>(x, w, out, bias, mean, var,
                                                    bnw, bnb, scale, M, N, K);
        softmax_rows<<<M, 256, 0, stream>>>(out, N);
    }
}

// Round 15
// 739.331 us; speedup vs baseline: 1.1043x; 1.1043x over previous
//
#include <hip/hip_runtime.h>

typedef _Float16 f16x8 __attribute__((ext_vector_type(8)));
typedef _Float16 f16x4 __attribute__((ext_vector_type(4)));
typedef float    f32x4 __attribute__((ext_vector_type(4)));

// ---------------------------------------------------------------- helpers

__device__ __forceinline__ void async16(void* lds, const void* g) {
    __builtin_amdgcn_global_load_lds(
        (const __attribute__((address_space(1))) unsigned int*)g,
        (__attribute__((address_space(3))) unsigned int*)lds, 16, 0, 0);
}

#define MEMF() asm volatile("" ::: "memory")
__device__ __forceinline__ void BAR() { MEMF(); __builtin_amdgcn_s_barrier(); MEMF(); }
#define VMWAIT(N) asm volatile("s_waitcnt vmcnt(" #N ")" ::: "memory")
#define LGKM0()   asm volatile("s_waitcnt lgkmcnt(0)" ::: "memory")
#define SBAR0()   __builtin_amdgcn_sched_barrier(0)

// 128B-row panel (128 rows x 64 fp16): 16B slot sig XORed by (row&7).
// 16 rr-rows x 4 kq: 2 lanes/slot-position => 2/bank = free (m136).
__device__ __forceinline__ f16x8 frag64(const char* panel, int row, int sig) {
    return *(const f16x8*)(panel + row * 128 + ((sig ^ (row & 7)) << 4));
}

// --------------------------- faithful m201-style 4-phase 256x256 GEMM, BK=64
// A [M][K] fp16, BT [N][K] fp16, z = (A*BT^T)*alpha+beta -> fp16 Z or fp32 C
// 8 waves (2Mx4N, wave 128x64 out), dbuf-2 LDS (128KiB = 2buf x 2half x 16KB
// per operand). Per K-tile 4 phases, each {ds_reads(8,8,4,4) ; 1 half-tile
// stage ; BAR ; lgkm0+sched_barrier ; setprio+16 MFMA ; BAR}; single counted
// VMWAIT(4) at P4 (never 0 in main loop).
//
// Ledger. Stage stream: T.P1->A0(T+1), T.P2->A1(T+1), T.P3->B0(T+2),
// T.P4->B1(T+2) (each half = 2 loads/thread). RAW: at T.P4, VMWAIT(4)
// retires all loads issued <= T.P2 => A0/A1(T+1) (T.P1/P2) and B0/B1(T+1)
// ((T-1).P3/P4) complete; BAR makes it block-wide => tile T+1 fully
// resident before any T+1 read. WAR: B regions fully read by P2's lgkm0
// (bf0@P1, bf1@P2) => stage into them at P3/P4 is >=1 barrier later; A
// regions fully read by P4's lgkm0 => restaged at next tile's P1/P2 (other
// buffer parity covers T+1; T+2 lands after T-end). Prologue stages
// B0(0),B1(0),A0(0),A1(0),B0(1),B1(1) then VMWAIT(4) (retires tile 0) +BAR.
// Tail: T==NT-2 -> VMWAIT(0); T==NT-1 -> no wait; stages guarded by <NT.

__global__ __launch_bounds__(512, 2) void gemm_f16_bn_4ph(
        const _Float16* __restrict__ A, const _Float16* __restrict__ BT,
        float* __restrict__ C, _Float16* __restrict__ Z,
        const float* __restrict__ bias, const float* __restrict__ mean,
        const float* __restrict__ var,  const float* __restrict__ bnw,
        const float* __restrict__ bnb,  const float* __restrict__ scalep,
        int M, int N, int K) {
    __shared__ __align__(16) char ldsA[2 * 32768];   // [buf][half][128][64] fp16
    __shared__ __align__(16) char ldsB[2 * 32768];

    // bijective XCD swizzle (grid = 1024, divisible by 8)
    const int nwg = gridDim.x;
    const int cpx = nwg >> 3;
    int bid = blockIdx.x;
    int swz = ((nwg & 7) == 0) ? (bid & 7) * cpx + (bid >> 3) : bid;
    const int ntn = N >> 8;
    const int m0 = (swz / ntn) << 8, n0 = (swz % ntn) << 8;

    const int t = threadIdx.x;
    const int lane = t & 63, wid = t >> 6;
    const int wr = wid >> 2, wc = wid & 3;          // 2M x 4N waves
    const int rr = lane & 15, kq = lane >> 4;

    const char* const paneA = ldsA + wr * 16384;          // + buf*32768
    const char* const paneB = ldsB + (wc >> 1) * 16384;   // + buf*32768
    const int browb = (wc & 1) * 64;

    // staging: half-panel = 128 rows x 64 cols fp16 = 1024 chunks of 16B;
    // thread owns chunks t (rows 0-63) and t+512 (rows 64-127). LDS dest
    // linear; global source 16B-slot pre-XORed by (row&7) (involution).
    const int r0 = t >> 3, r1 = (t + 512) >> 3;
    const int s0 = ((t & 7) ^ (r0 & 7)) << 3;
    const int s1 = ((t & 7) ^ (r1 & 7)) << 3;
    const _Float16* const gA0 = A  + (size_t)(m0 + r0) * K + s0;
    const _Float16* const gA1 = A  + (size_t)(m0 + r1) * K + s1;
    const _Float16* const gB0 = BT + (size_t)(n0 + r0) * K + s0;
    const _Float16* const gB1 = BT + (size_t)(n0 + r1) * K + s1;
    char* const adst = ldsA + (size_t)t * 16;
    char* const bdst = ldsB + (size_t)t * 16;
    const size_t hstep = (size_t)128 * K;   // half-panel row offset (halfs)

#define STG_A(BUF, H, T_) do {                                            \
    const size_t o_ = (size_t)(H) * hstep + (size_t)(T_) * 64;            \
    char* d_ = adst + (BUF) * 32768 + (H) * 16384;                        \
    async16(d_,        gA0 + o_);                                         \
    async16(d_ + 8192, gA1 + o_);                                         \
  } while (0)
#define STG_B(BUF, H, T_) do {                                            \
    const size_t o_ = (size_t)(H) * hstep + (size_t)(T_) * 64;            \
    char* d_ = bdst + (BUF) * 32768 + (H) * 16384;                        \
    async16(d_,        gB0 + o_);                                         \
    async16(d_ + 8192, gB1 + o_);                                         \
  } while (0)

    f16x8 aF[4], bf0[4], bf1[4];
    f32x4 acc[8][4] = {};

    const int NT = K >> 6;   // host gate: NT>=4, NT even

    // prologue: B0(0),B1(0),A0(0),A1(0),B0(1),B1(1); retire tile 0
    STG_B(0, 0, 0); STG_B(0, 1, 0); STG_A(0, 0, 0); STG_A(0, 1, 0);
    STG_B(1, 0, 1); STG_B(1, 1, 1);
    VMWAIT(4);
    BAR();

#define MFMA16(MB, BF)                                                    \
    __builtin_amdgcn_s_setprio(1);                                        \
    _Pragma("unroll")                                                     \
    for (int ni = 0; ni < 4; ni++) {                                      \
      _Pragma("unroll")                                                   \
      for (int mi = 0; mi < 4; mi++)                                      \
        acc[(MB) * 4 + mi][ni] = __builtin_amdgcn_mfma_f32_16x16x32_f16(  \
            aF[mi], BF[ni], acc[(MB) * 4 + mi][ni], 0, 0, 0);             \
    }                                                                     \
    __builtin_amdgcn_s_setprio(0)

#define TILE(B_, T_)                                                      \
  do {                                                                    \
    const char* pa = paneA + (B_) * 32768;                                \
    const char* pb = paneB + (B_) * 32768;                                \
    /* P1: B ks0 + A mi0-3 ks0 ; stage A0(T+1) */                         \
    _Pragma("unroll")                                                     \
    for (int ni = 0; ni < 4; ni++) bf0[ni] = frag64(pb, browb + ni * 16 + rr, kq);      \
    _Pragma("unroll")                                                     \
    for (int mi = 0; mi < 4; mi++) aF[mi] = frag64(pa, mi * 16 + rr, kq);               \
    if ((T_) + 1 < NT) STG_A((B_) ^ 1, 0, (T_) + 1);                      \
    BAR(); LGKM0(); SBAR0();                                              \
    MFMA16(0, bf0);                                                       \
    BAR();                                                                \
    /* P2: B ks1 + A mi0-3 ks1 ; stage A1(T+1) */                         \
    _Pragma("unroll")                                                     \
    for (int ni = 0; ni < 4; ni++) bf1[ni] = frag64(pb, browb + ni * 16 + rr, kq + 4);  \
    _Pragma("unroll")                                                     \
    for (int mi = 0; mi < 4; mi++) aF[mi] = frag64(pa, mi * 16 + rr, kq + 4);           \
    if ((T_) + 1 < NT) STG_A((B_) ^ 1, 1, (T_) + 1);                      \
    BAR(); LGKM0(); SBAR0();                                              \
    MFMA16(0, bf1);                                                       \
    BAR();                                                                \
    /* P3: A mi4-7 ks0 ; stage B0(T+2) */                                 \
    _Pragma("unroll")                                                     \
    for (int mi = 0; mi < 4; mi++) aF[mi] = frag64(pa, 64 + mi * 16 + rr, kq);          \
    if ((T_) + 2 < NT) STG_B(B_, 0, (T_) + 2);                            \
    BAR(); LGKM0(); SBAR0();                                              \
    MFMA16(1, bf0);                                                       \
    BAR();                                                                \
    /* P4: A mi4-7 ks1 ; stage B1(T+2) ; counted wait */                  \
    _Pragma("unroll")                                                     \
    for (int mi = 0; mi < 4; mi++) aF[mi] = frag64(pa, 64 + mi * 16 + rr, kq + 4);      \
    if ((T_) + 2 < NT) STG_B(B_, 1, (T_) + 2);                            \
    BAR(); LGKM0(); SBAR0();                                              \
    MFMA16(1, bf1);                                                       \
    if ((T_) + 2 < NT)       { VMWAIT(4); }                               \
    else if ((T_) + 2 == NT) { VMWAIT(0); }                               \
    BAR();                                                                \
  } while (0)

    for (int T = 0; T < NT; T += 2) {
        TILE(0, T);
        TILE(1, T + 1);
    }
#undef TILE
#undef MFMA16
#undef STG_A
#undef STG_B

    // fused BN-affine epilogue (r8/r13 wave-tile layout): fp16 Z or fp32 C
    const float s = scalep[0];
    const int colb = n0 + wc * 64 + rr;
    const int rowb = m0 + wr * 128 + (kq << 2);
#pragma unroll
    for (int ni = 0; ni < 4; ni++) {
        const int col = colb + ni * 16;
        const float rv    = rsqrtf(var[col] + 1e-5f);
        const float alpha = rv * bnw[col] * s;
        const float beta  = (bias[col] - mean[col]) * alpha + bnb[col] * s;
#pragma unroll
        for (int mi = 0; mi < 8; mi++)
#pragma unroll
            for (int i = 0; i < 4; i++) {
                const float v = acc[mi][ni][i] * alpha + beta;
                const size_t off = (size_t)(rowb + mi * 16 + i) * N + col;
                if (Z) Z[off] = (_Float16)v;
                else   __builtin_nontemporal_store(v, &C[off]);
            }
    }
}

// ---------------------------------------------------------------- converts

__global__ __launch_bounds__(256) void cvt_x_kernel(const float4* __restrict__ in,
                                                    f16x4* __restrict__ outp, long n4) {
    long i = (long)blockIdx.x * blockDim.x + threadIdx.x;
    const long stride = (long)gridDim.x * blockDim.x;
    for (; i < n4; i += stride) {
        float4 v = in[i];
        f16x4 h = { (_Float16)v.x, (_Float16)v.y, (_Float16)v.z, (_Float16)v.w };
        outp[i] = h;
    }
}

// w [K][N] fp32 -> wt [N][K] fp16
__global__ __launch_bounds__(256) void transpose_w_kernel(const float* __restrict__ w,
                                                          _Float16* __restrict__ wt,
                                                          int K, int N) {
    __shared__ _Float16 tile[32][33];
    const int n0 = blockIdx.x * 32;
    const int k0 = blockIdx.y * 32;
    for (int i = threadIdx.y; i < 32; i += 8)
        tile[i][threadIdx.x] = (_Float16)w[(size_t)(k0 + i) * N + n0 + threadIdx.x];
    __syncthreads();
    for (int i = threadIdx.y; i < 32; i += 8)
        wt[(size_t)(n0 + i) * K + k0 + threadIdx.x] = tile[threadIdx.x][i];
}

// ------------------------------------------------- fallback GEMM (no ws)

__device__ __forceinline__ void mfma_step_128(const _Float16* As, const _Float16* Bs,
                                              f32x4 (&acc)[4][4], int lane, int wr, int wc) {
    const int kk = (lane >> 4) * 8;
    const int rr = lane & 15;
    f16x8 af[4], bf[4];
#pragma unroll
    for (int mi = 0; mi < 4; mi++)
        af[mi] = *(const f16x8*)(As + (size_t)(wr * 64 + mi * 16 + rr) * 32 + kk);
#pragma unroll
    for (int ni = 0; ni < 4; ni++)
        bf[ni] = *(const f16x8*)(Bs + (size_t)(wc * 64 + ni * 16 + rr) * 32 + kk);
#pragma unroll
    for (int mi = 0; mi < 4; mi++)
#pragma unroll
        for (int ni = 0; ni < 4; ni++)
            acc[mi][ni] = __builtin_amdgcn_mfma_f32_16x16x32_f16(af[mi], bf[ni], acc[mi][ni], 0, 0, 0);
}

__global__ __launch_bounds__(256) void gemm_f32src_bn(const float* __restrict__ X,
                                                      const float* __restrict__ W,
                                                      float* __restrict__ C,
                                                      const float* __restrict__ bias,
                                                      const float* __restrict__ mean,
                                                      const float* __restrict__ var,
                                                      const float* __restrict__ bnw,
                                                      const float* __restrict__ bnb,
                                                      const float* __restrict__ scalep,
                                                      int M, int N, int K) {
    __shared__ _Float16 As[128 * 32];
    __shared__ _Float16 Bs[128 * 32];

    const int nwg = gridDim.x;
    const int cpx = nwg >> 3;
    int bid = blockIdx.x;
    int swz = ((nwg & 7) == 0) ? (bid & 7) * cpx + (bid >> 3) : bid;
    const int ntn = N / 128;
    const int m0 = (swz / ntn) * 128, n0 = (swz % ntn) * 128;

    const int t = threadIdx.x;
    const int lane = t & 63, w = t >> 6;
    const int wr = w >> 1, wc = w & 1;

    f32x4 acc[4][4] = {};

    for (int k0 = 0; k0 < K; k0 += 32) {
        __syncthreads();
#pragma unroll
        for (int p = 0; p < 4; p++) {
            const int r = p * 32 + (t >> 3);
            const int c = (t & 7) * 4;
            float4 v = *(const float4*)&X[(size_t)(m0 + r) * K + k0 + c];
            f16x4 h = { (_Float16)v.x, (_Float16)v.y, (_Float16)v.z, (_Float16)v.w };
            *(f16x4*)&As[(size_t)r * 32 + c] = h;
        }
#pragma unroll
        for (int p = 0; p < 4; p++) {
            const int kk = p * 8 + (t >> 5);
            const int nn = (t & 31) * 4;
            float4 v = *(const float4*)&W[(size_t)(k0 + kk) * N + n0 + nn];
            Bs[(size_t)(nn + 0) * 32 + kk] = (_Float16)v.x;
            Bs[(size_t)(nn + 1) * 32 + kk] = (_Float16)v.y;
            Bs[(size_t)(nn + 2) * 32 + kk] = (_Float16)v.z;
            Bs[(size_t)(nn + 3) * 32 + kk] = (_Float16)v.w;
        }
        __syncthreads();
        mfma_step_128(As, Bs, acc, lane, wr, wc);
    }

    const float s = scalep[0];
    const int colbase = n0 + wc * 64 + (lane & 15);
    const int rowbase = m0 + wr * 64 + ((lane >> 4) << 2);
#pragma unroll
    for (int ni = 0; ni < 4; ni++) {
        const int col = colbase + ni * 16;
        const float r     = rsqrtf(var[col] + 1e-5f);
        const float alpha = r * bnw[col] * s;
        const float beta  = (bias[col] - mean[col]) * alpha + bnb[col] * s;
#pragma unroll
        for (int mi = 0; mi < 4; mi++)
#pragma unroll
            for (int i = 0; i < 4; i++)
                C[(size_t)(rowbase + mi * 16 + i) * N + col] = acc[mi][ni][i] * alpha + beta;
    }
}

// ---------------------------------------------------------------- softmax

__global__ __launch_bounds__(256) void softmax_rows(float* __restrict__ out, int N) {
    __shared__ float red[8];
    float4* p = (float4*)(out + (size_t)blockIdx.x * N);
    const int t = threadIdx.x;
    const int lane = t & 63, wid = t >> 6;

    float4 v[4];
    float mx = -3.4e38f;
#pragma unroll
    for (int i = 0; i < 4; i++) {
        v[i] = p[t + 256 * i];
        mx = fmaxf(mx, fmaxf(fmaxf(v[i].x, v[i].y), fmaxf(v[i].z, v[i].w)));
    }
#pragma unroll
    for (int off = 32; off >= 1; off >>= 1) mx = fmaxf(mx, __shfl_xor(mx, off));
    if (lane == 0) red[wid] = mx;
    __syncthreads();
    mx = fmaxf(fmaxf(red[0], red[1]), fmaxf(red[2], red[3]));

    float sum = 0.f;
#pragma unroll
    for (int i = 0; i < 4; i++) {
        v[i].x = __expf(v[i].x - mx); v[i].y = __expf(v[i].y - mx);
        v[i].z = __expf(v[i].z - mx); v[i].w = __expf(v[i].w - mx);
        sum += v[i].x + v[i].y + v[i].z + v[i].w;
    }
#pragma unroll
    for (int off = 32; off >= 1; off >>= 1) sum += __shfl_xor(sum, off);
    if (lane == 0) red[4 + wid] = sum;
    __syncthreads();
    sum = red[4] + red[5] + red[6] + red[7];

    const float inv = 1.0f / sum;
#pragma unroll
    for (int i = 0; i < 4; i++) {
        v[i].x *= inv; v[i].y *= inv; v[i].z *= inv; v[i].w *= inv;
        p[t + 256 * i] = v[i];
    }
}

// fp16-z variant: reads z fp16 (half the read bytes), writes fp32 probs
__global__ __launch_bounds__(256) void softmax_rows_h(const _Float16* __restrict__ z,
                                                      float* __restrict__ out, int N) {
    __shared__ float red[8];
    const _Float16* zr = z + (size_t)blockIdx.x * N;
    float4* o4 = (float4*)(out + (size_t)blockIdx.x * N);
    const int t = threadIdx.x;
    const int lane = t & 63, wid = t >> 6;

    f16x8 h0 = *(const f16x8*)(zr + t * 8);
    f16x8 h1 = *(const f16x8*)(zr + 2048 + t * 8);
    float v[16];
#pragma unroll
    for (int i = 0; i < 8; i++) { v[i] = (float)h0[i]; v[8 + i] = (float)h1[i]; }

    float mx = -3.4e38f;
#pragma unroll
    for (int i = 0; i < 16; i++) mx = fmaxf(mx, v[i]);
#pragma unroll
    for (int off = 32; off >= 1; off >>= 1) mx = fmaxf(mx, __shfl_xor(mx, off));
    if (lane == 0) red[wid] = mx;
    __syncthreads();
    mx = fmaxf(fmaxf(red[0], red[1]), fmaxf(red[2], red[3]));

    float sum = 0.f;
#pragma unroll
    for (int i = 0; i < 16; i++) { v[i] = __expf(v[i] - mx); sum += v[i]; }
#pragma unroll
    for (int off = 32; off >= 1; off >>= 1) sum += __shfl_xor(sum, off);
    if (lane == 0) red[4 + wid] = sum;
    __syncthreads();
    sum = red[4] + red[5] + red[6] + red[7];

    const float inv = 1.0f / sum;
    float4 o;
#pragma unroll
    for (int c = 0; c < 4; c++) {
        o.x = v[c * 4 + 0] * inv; o.y = v[c * 4 + 1] * inv;
        o.z = v[c * 4 + 2] * inv; o.w = v[c * 4 + 3] * inv;
        o4[(c >> 1) * 512 + t * 2 + (c & 1)] = o;
    }
}

// ---------------------------------------------------------------- launch

extern "C" void kernel_launch(void* const* d_in, const int* in_sizes, int n_in,
                              void* d_out, int out_size, void* d_ws, size_t ws_size,
                              hipStream_t stream) {
    const float* x     = (const float*)d_in[0];
    const float* w     = (const float*)d_in[1];
    const float* bias  = (const float*)d_in[2];
    const float* mean  = (const float*)d_in[3];
    const float* var   = (const float*)d_in[4];
    const float* bnw   = (const float*)d_in[5];
    const float* bnb   = (const float*)d_in[6];
    const float* scale = (const float*)d_in[7];
    float* out = (float*)d_out;

    const int N = in_sizes[2];
    const int K = in_sizes[1] / N;
    const int M = in_sizes[0] / K;

    const size_t xh_bytes = (size_t)M * K * sizeof(_Float16);
    const size_t wh_bytes = (size_t)N * K * sizeof(_Float16);
    const size_t zh_bytes = (size_t)M * N * sizeof(_Float16);
    const int NT = K >> 6;

    if (ws_size >= xh_bytes + wh_bytes && (M & 255) == 0 && (N & 255) == 0 &&
        (K & 63) == 0 && NT >= 4 && (NT & 1) == 0) {
        _Float16* x16 = (_Float16*)d_ws;
        _Float16* wt16 = (_Float16*)((char*)d_ws + xh_bytes);
        const bool zf16 = (ws_size >= xh_bytes + wh_bytes + zh_bytes) && (N & 4095) == 0;
        _Float16* z16 = zf16 ? (_Float16*)((char*)d_ws + xh_bytes + wh_bytes) : nullptr;

        cvt_x_kernel<<<2048, 256, 0, stream>>>((const float4*)x, (f16x4*)x16,
                                               (long)M * K / 4);
        transpose_w_kernel<<<dim3(N / 32, K / 32), dim3(32, 8), 0, stream>>>(w, wt16, K, N);
        const int nblocks = (M >> 8) * (N >> 8);
        gemm_f16_bn_4ph<<<nblocks, 512, 0, stream>>>(x16, wt16, out, z16, bias, mean,
                                                     var, bnw, bnb, scale, M, N, K);
        if (zf16) softmax_rows_h<<<M, 256, 0, stream>>>(z16, out, N);
        else      softmax_rows<<<M, 256, 0, stream>>>(out, N);
    } else {
        const int nblocks = (M / 128) * (N / 128);
        gemm_f32src_bn<<<nblocks, 256, 0, stream>>>(x, w, out, bias, mean, var,
                                                    bnw, bnb, scale, M, N, K);
        softmax_rows<<<M, 256, 0, stream>>>(out, N);
    }
}